// Round 4
// baseline (657.026 us; speedup 1.0000x reference)
//
#include <hip/hip_runtime.h>
#include <hip/hip_bf16.h>
#include <hip/hip_fp16.h>
#include <math.h>

#define NN   100000   // nodes
#define NNP  100096   // nodes padded to mult of 128 (GEMM staging reads, zero-filled)
#define DD   202      // feature dim
#define ET   6        // edge types
#define MM   200000   // edges per type
#define NE   (ET*MM)  // 1.2M edges
#define NPOS 512
#define GDP  256      // gating row stride in fp16 halves (512 B rows, zeros at 202..255)
#define DE   1212     // DD*ET
#define PDE  1216     // prop row stride (padded; 2432 B rows -> 16B-aligned, 64B-aligned)
#define KK   202      // GEMM K
#define KP   224      // K padded to 7*32
#define NP   1280     // N padded to 10*128

#define EG   4        // gather: edges per pipeline group
#define SLOT 1024     // gather: LDS bytes per edge (prop 512 + gating 512)

typedef __attribute__((ext_vector_type(8))) short bf16x8;
typedef __attribute__((ext_vector_type(4))) float f32x4;

static __device__ inline unsigned short f2b(float f) {
    union { __hip_bfloat16 h; unsigned short s; } u;
    u.h = __float2bfloat16(f);
    return u.s;
}

static __device__ inline void glds16(const unsigned short* g, unsigned short* l) {
    __builtin_amdgcn_global_load_lds(
        (const __attribute__((address_space(1))) unsigned int*)g,
        (__attribute__((address_space(3))) unsigned int*)l, 16, 0, 0);
}

static __device__ inline void glds4(const void* g, void* l) {
    __builtin_amdgcn_global_load_lds(
        (const __attribute__((address_space(1))) unsigned int*)g,
        (__attribute__((address_space(3))) unsigned int*)l, 4, 0, 0);
}

// ---------------- pos_gating: (512 x GDP) fp16 = 2*sigmoid(pos_embs @ W_pos + b_pos)
__global__ void gating_kernel(const float* __restrict__ W_pos,
                              const float* __restrict__ b_pos,
                              unsigned short* __restrict__ gat) {
    int p = blockIdx.x;
    __shared__ float emb[DD];
    int t = threadIdx.x;
    if (t < 100) {
        float invf = expf(-((float)t / 100.0f) * 9.210340371976184f); // ln(10000)
        float si = (float)p * invf;
        emb[t]       = sinf(si);
        emb[100 + t] = cosf(si);
    } else if (t < 102) {
        emb[100 + t] = 0.0f;
    }
    __syncthreads();
    if (t < GDP) {
        float g = 0.0f;
        if (t < DD) {
            float acc = b_pos[t];
            for (int k = 0; k < DD; ++k) acc += emb[k] * W_pos[k * DD + t];
            g = 2.0f / (1.0f + expf(-acc));
        }
        union { __half h; unsigned short s; } u;
        u.h = __float2half_rn(g);
        gat[p * GDP + t] = u.s;   // fp16; zeros at 202..255
    }
}

// ---------------- W_transform (202x1212 fp32) -> Bt (1280x224 bf16, transposed, padded)
__global__ void convB_kernel(const float* __restrict__ W, unsigned short* __restrict__ Bt) {
    int id = blockIdx.x * 256 + threadIdx.x;
    if (id >= NP * KP) return;
    int n = id / KP, k = id % KP;
    float v = (k < KK && n < DE) ? W[(size_t)k * DE + n] : 0.0f;
    Bt[id] = f2b(v);
}

// ---------------- node_states (100000x202 fp32) -> Abf (100096x224 bf16, padded)
__global__ void convA_kernel(const float* __restrict__ A, unsigned short* __restrict__ Abf) {
    int id = blockIdx.x * 256 + threadIdx.x;         // one bf16 pair per thread
    if (id >= NNP * (KP / 2)) return;
    int row = id / (KP / 2), kp = (id % (KP / 2)) * 2;
    float2 v = make_float2(0.0f, 0.0f);
    if (row < NN && kp < KK) v = *(const float2*)&A[(size_t)row * KK + kp]; // kp<=200 -> ok
    ushort2 o; o.x = f2b(v.x); o.y = f2b(v.y);
    *(ushort2*)&Abf[(size_t)row * KP + kp] = o;
}

// ---------------- prop = Abf @ Bt^T + b -> bf16[NN][PDE], MFMA 128x128 tile
__global__ __launch_bounds__(256) void gemm_mfma(const unsigned short* __restrict__ Abf,
                                                 const unsigned short* __restrict__ Bt,
                                                 const float* __restrict__ bias,
                                                 unsigned short* __restrict__ C) {
    __shared__ unsigned short sA[4096];   // 128 rows x 32 k (swizzled chunks)
    __shared__ unsigned short sB[4096];
    __shared__ unsigned short sE[4608];   // epilogue: 4 waves x 16 rows x 72 (stride-padded)
    int t    = threadIdx.x;
    int lane = t & 63;
    int wave = t >> 6;
    int q    = lane >> 4;
    int r16  = lane & 15;
    int wm   = (wave >> 1) * 64;
    int wn   = (wave & 1) * 64;
    int row0 = blockIdx.y * 128;
    int col0 = blockIdx.x * 128;

    int lrow = lane >> 2;
    int gch  = (lane & 3) ^ ((lrow >> 1) & 3);     // global k-chunk this lane fetches
    const unsigned short* aS0 = Abf + (size_t)(row0 + wave * 32 + lrow) * KP + gch * 8;
    const unsigned short* aS1 = aS0 + 16 * KP;
    const unsigned short* bS0 = Bt  + (size_t)(col0 + wave * 32 + lrow) * KP + gch * 8;
    const unsigned short* bS1 = bS0 + 16 * KP;
    unsigned short* lA0 = &sA[(wave * 32) * 32];
    unsigned short* lA1 = &sA[(wave * 32 + 16) * 32];
    unsigned short* lB0 = &sB[(wave * 32) * 32];
    unsigned short* lB1 = &sB[(wave * 32 + 16) * 32];

    f32x4 acc[4][4] = {};
    int swzr = (r16 >> 1) & 3;

    for (int kc = 0; kc < KP; kc += 32) {
        glds16(aS0 + kc, lA0);
        glds16(aS1 + kc, lA1);
        glds16(bS0 + kc, lB0);
        glds16(bS1 + kc, lB1);
        __syncthreads();

        bf16x8 a[4], b[4];
        #pragma unroll
        for (int mi = 0; mi < 4; ++mi)
            a[mi] = *(const bf16x8*)&sA[(wm + mi * 16 + r16) * 32 + (q ^ swzr) * 8];
        #pragma unroll
        for (int ni = 0; ni < 4; ++ni)
            b[ni] = *(const bf16x8*)&sB[(wn + ni * 16 + r16) * 32 + (q ^ swzr) * 8];
        #pragma unroll
        for (int mi = 0; mi < 4; ++mi)
            #pragma unroll
            for (int ni = 0; ni < 4; ++ni)
                acc[mi][ni] = __builtin_amdgcn_mfma_f32_16x16x32_bf16(a[mi], b[ni], acc[mi][ni], 0, 0, 0);
        __syncthreads();
    }

    float bb[4];
    #pragma unroll
    for (int ni = 0; ni < 4; ++ni) {
        int col = col0 + wn + ni * 16 + r16;
        bb[ni] = (col < DE) ? bias[col] : 0.0f;
    }
    int epi = wave * 1152;            // 16 rows * 72
    int rl = lane >> 3, ck = lane & 7;
    #pragma unroll
    for (int mi = 0; mi < 4; ++mi) {
        #pragma unroll
        for (int ni = 0; ni < 4; ++ni)
            #pragma unroll
            for (int ri = 0; ri < 4; ++ri)
                sE[epi + (q * 4 + ri) * 72 + ni * 16 + r16] = f2b(acc[mi][ni][ri] + bb[ni]);
        #pragma unroll
        for (int ii = 0; ii < 2; ++ii) {
            int rr = ii * 8 + rl;
            bf16x8 v = *(const bf16x8*)&sE[epi + rr * 72 + ck * 8];
            int grow = row0 + wm + mi * 16 + rr;
            int gcol = col0 + wn + ck * 8;
            if (grow < NN && gcol < PDE)
                *(bf16x8*)&C[(size_t)grow * PDE + gcol] = v;
        }
    }
}

// ---------------- pass 1: histogram of targets
__global__ __launch_bounds__(256) void count_kernel(const int* __restrict__ edges,
                                                    int* __restrict__ count) {
    int i = blockIdx.x * 256 + threadIdx.x;
    if (i >= NE) return;
    atomicAdd(&count[edges[2 * i + 1]], 1);
}

// ---------------- pass 2: segment allocation (block scan + 1 atomic/block)
__global__ __launch_bounds__(256) void alloc_kernel(const int* __restrict__ count,
                                                    int* __restrict__ start,
                                                    int* __restrict__ cursor) {
    int t = blockIdx.x * 256 + threadIdx.x;
    int c = (t < NN) ? count[t] : 0;
    __shared__ int s[256];
    __shared__ int base;
    s[threadIdx.x] = c;
    __syncthreads();
    int v = c;
    for (int off = 1; off < 256; off <<= 1) {
        int u = (threadIdx.x >= off) ? s[threadIdx.x - off] : 0;
        __syncthreads();
        v += u;
        s[threadIdx.x] = v;
        __syncthreads();
    }
    if (threadIdx.x == 255) base = atomicAdd(cursor, v);
    __syncthreads();
    if (t < NN) start[t] = base + v - c;
}

// ---------------- pass 3: scatter PACKED edge records (start becomes segment END)
// record: src (17b) | e (3b) | pos (9b)
__global__ __launch_bounds__(256) void scatter_kernel(const int* __restrict__ edges,
                                                      const int* __restrict__ pos_lists,
                                                      int* __restrict__ start,
                                                      unsigned* __restrict__ recs) {
    int i = blockIdx.x * 256 + threadIdx.x;
    if (i >= NE) return;
    int2 st = *(const int2*)&edges[2 * i];              // (src, tgt), 8B aligned
    int e = (int)((unsigned)i / MM);                    // edge type
    unsigned rec = (unsigned)st.x | ((unsigned)e << 17) | ((unsigned)pos_lists[i] << 20);
    int p = atomicAdd(&start[st.y], 1);
    recs[p] = rec;
}

// ---------------- pass 4: one wave per target; async global_load_lds pipeline.
// Per 4-edge group: 16 width-4 DMA ops (prop 512B + fp16 gating 512B per edge)
// into a wave-private double-buffered LDS slot; counted vmcnt(16) waits only for
// the PREVIOUS group -> 8 edges of requests permanently in flight per wave.
// DMA has no dest register, so the compiler CANNOT re-serialize it (the failure
// mode of rounds 1-2). Row-base broadcast via v_readlane (no ds_bpermute).
// Edge accumulation order unchanged (same numerics as the passing round-2).

#define VMW16 do { asm volatile("s_waitcnt vmcnt(16)" ::: "memory"); \
                   __builtin_amdgcn_sched_barrier(0); } while (0)
#define VMW0  do { asm volatile("s_waitcnt vmcnt(0)"  ::: "memory"); \
                   __builtin_amdgcn_sched_barrier(0); } while (0)
#define LKW0  do { asm volatile("s_waitcnt lgkmcnt(0)" ::: "memory"); \
                   __builtin_amdgcn_sched_barrier(0); } while (0)

#define ISSUE(G)                                                          \
  {                                                                       \
    LKW0;  /* prior consume's ds_reads drained before slot overwrite */   \
    char* slot_ = wlds + (((G) & 1) * (EG * SLOT));                       \
    _Pragma("unroll")                                                     \
    for (int u_ = 0; u_ < EG; ++u_) {                                     \
      int j_ = (G) * EG + u_; if (j_ >= n) j_ = n - 1;                    \
      int pb_ = __builtin_amdgcn_readlane(pby, j_);                       \
      int gb_ = __builtin_amdgcn_readlane(gby, j_);                       \
      char* sl_ = slot_ + u_ * SLOT;                                      \
      glds4(prop8 + pb_ +       lane * 4, sl_);                           \
      glds4(prop8 + pb_ + 256 + lane * 4, sl_ + 256);                     \
      glds4(gat8  + gb_ +       lane * 4, sl_ + 512);                     \
      glds4(gat8  + gb_ + 256 + lane * 4, sl_ + 768);                     \
    }                                                                     \
  }

#define CONSUME(G)                                                        \
  {                                                                       \
    char* slot_ = wlds + (((G) & 1) * (EG * SLOT));                       \
    _Pragma("unroll")                                                     \
    for (int u_ = 0; u_ < EG; ++u_) {                                     \
      if ((G) * EG + u_ < n) {                                            \
        uint2 pv_ = *(const uint2*)(slot_ + u_ * SLOT + dd2);             \
        uint2 gv_ = *(const uint2*)(slot_ + u_ * SLOT + 512 + dd2);       \
        float2 g01_ = __half22float2(*(const __half2*)&gv_.x);            \
        float2 g23_ = __half22float2(*(const __half2*)&gv_.y);            \
        a0 += __uint_as_float(pv_.x << 16)         * g01_.x;              \
        a1 += __uint_as_float(pv_.x & 0xffff0000u) * g01_.y;              \
        a2 += __uint_as_float(pv_.y << 16)         * g23_.x;              \
        a3 += __uint_as_float(pv_.y & 0xffff0000u) * g23_.y;              \
      }                                                                   \
    }                                                                     \
  }

__global__ __launch_bounds__(256) void gather_kernel(const unsigned short* __restrict__ prop,
                                                     const unsigned short* __restrict__ gat,
                                                     const int* __restrict__ count,
                                                     const int* __restrict__ seg_end,
                                                     const unsigned* __restrict__ recs,
                                                     float* __restrict__ out) {
    __shared__ __align__(16) char lds[4 * 2 * EG * SLOT];   // 32 KB: 4 waves x dbuf x 4 KB
    int wave = threadIdx.x >> 6;
    int lane = threadIdx.x & 63;
    char* wlds = &lds[wave * (2 * EG * SLOT)];
    int wid = blockIdx.x * 4 + wave;
    if (wid >= NN) return;
    int c = count[wid];
    int end = seg_end[wid];
    int begin = end - c;
    int d = lane * 4;
    bool act = d < DD;                    // lanes 0..50
    int dd2 = d * 2;                      // byte offset into 512-B staged rows
    const char* prop8 = (const char*)prop;
    const char* gat8  = (const char*)gat;
    float a0 = 0.f, a1 = 0.f, a2 = 0.f, a3 = 0.f;

    for (int base = begin; base < end; base += 64) {
        int n = end - base; if (n > 64) n = 64;
        unsigned rec = 0u;
        if (lane < n) rec = recs[base + lane];
        int pby = ((int)(rec & 0x1FFFFu) * PDE + (int)((rec >> 17) & 7u) * DD) * 2; // bytes
        int gby = (int)(rec >> 20) << 9;                                            // x512 B

        int ng = (n + EG - 1) >> 2;
        ISSUE(0);
        for (int g = 0; g < ng; ++g) {
            if (g + 1 < ng) { ISSUE(g + 1); VMW16; } else { VMW0; }
            CONSUME(g);
        }
    }

    float div = (c == 0 ? 1.0f : (float)c) + 1e-8f;
    float inv = 1.0f / div;
    if (act) {
        float* orow = out + (size_t)wid * DD;
        *(float2*)&orow[d] = make_float2(a0 * inv, a1 * inv);
        if (d + 2 < DD) *(float2*)&orow[d + 2] = make_float2(a2 * inv, a3 * inv);
    }
}

extern "C" void kernel_launch(void* const* d_in, const int* in_sizes, int n_in,
                              void* d_out, int out_size, void* d_ws, size_t ws_size,
                              hipStream_t stream) {
    const float* node_states = (const float*)d_in[0];
    const int*   edges       = (const int*)d_in[1];
    const int*   pos_lists   = (const int*)d_in[2];
    const float* W_transform = (const float*)d_in[3];
    const float* b_transform = (const float*)d_in[4];
    const float* W_pos       = (const float*)d_in[5];
    const float* b_pos       = (const float*)d_in[6];
    float* out = (float*)d_out;

    // workspace layout (16B-aligned blocks); total ~294.5 MB (< round-2's 294.63)
    char* ws = (char*)d_ws;
    unsigned short* gat = (unsigned short*)ws;  ws += (size_t)NPOS * GDP * 2;  // 262,144 B
    int* count  = (int*)ws;                     ws += (size_t)NN * 4;          // 400,000 B
    int* start  = (int*)ws;                     ws += (size_t)NN * 4;          // 400,000 B
    int* cursor = (int*)ws;                     ws += 16;
    unsigned short* Bt  = (unsigned short*)ws;  ws += (size_t)NP * KP * 2;     // 573,440 B
    unsigned short* Abf = (unsigned short*)ws;  ws += (size_t)NNP * KP * 2;    // 44,843,008 B
    unsigned* recs = (unsigned*)ws;             ws += (size_t)NE * 4;          // 4,800,000 B
    unsigned short* prop = (unsigned short*)ws; // 243,200,000 B + 512 B staging over-read pad

    hipMemsetAsync(count, 0, NN * sizeof(int), stream);
    hipMemsetAsync(cursor, 0, sizeof(int), stream);

    gating_kernel<<<NPOS, 256, 0, stream>>>(W_pos, b_pos, gat);
    convB_kernel<<<(NP * KP + 255) / 256, 256, 0, stream>>>(W_transform, Bt);
    convA_kernel<<<(NNP * (KP / 2) + 255) / 256, 256, 0, stream>>>(node_states, Abf);

    dim3 g2(NP / 128, NNP / 128);
    gemm_mfma<<<g2, 256, 0, stream>>>(Abf, Bt, b_transform, prop);

    count_kernel<<<(NE + 255) / 256, 256, 0, stream>>>(edges, count);
    alloc_kernel<<<(NN + 255) / 256, 256, 0, stream>>>(count, start, cursor);
    scatter_kernel<<<(NE + 255) / 256, 256, 0, stream>>>(edges, pos_lists, start, recs);
    gather_kernel<<<(NN + 3) / 4, 256, 0, stream>>>(prop, gat, count, start, recs, out);
}

// Round 6
// 631.811 us; speedup vs baseline: 1.0399x; 1.0399x over previous
//
#include <hip/hip_runtime.h>
#include <hip/hip_bf16.h>
#include <hip/hip_fp16.h>
#include <math.h>

#define NN   100000   // nodes
#define NNP  100096   // nodes padded to mult of 128 (GEMM staging reads, zero-filled)
#define DD   202      // feature dim
#define ET   6        // edge types
#define MM   200000   // edges per type
#define NE   (ET*MM)  // 1.2M edges
#define NPOS 512
#define GDP  204      // gating row stride (fp16 elements; 408-B rows, zeros at 202..203)
#define DE   1212     // DD*ET
#define PDE  1216     // prop row stride (padded; 2432 B rows -> 16B-aligned, 64B-aligned)
#define KK   202      // GEMM K
#define KP   224      // K padded to 7*32
#define NP   1280     // N padded to 10*128

typedef __attribute__((ext_vector_type(8))) short bf16x8;
typedef __attribute__((ext_vector_type(4))) float f32x4;

static __device__ inline unsigned short f2b(float f) {
    union { __hip_bfloat16 h; unsigned short s; } u;
    u.h = __float2bfloat16(f);
    return u.s;
}

static __device__ inline void glds16(const unsigned short* g, unsigned short* l) {
    __builtin_amdgcn_global_load_lds(
        (const __attribute__((address_space(1))) unsigned int*)g,
        (__attribute__((address_space(3))) unsigned int*)l, 16, 0, 0);
}

// ---------------- pos_gating: (512 x GDP) fp16 = 2*sigmoid(pos_embs @ W_pos + b_pos)
__global__ void gating_kernel(const float* __restrict__ W_pos,
                              const float* __restrict__ b_pos,
                              unsigned short* __restrict__ gat) {
    int p = blockIdx.x;
    __shared__ float emb[DD];
    int t = threadIdx.x;
    if (t < 100) {
        float invf = expf(-((float)t / 100.0f) * 9.210340371976184f); // ln(10000)
        float si = (float)p * invf;
        emb[t]       = sinf(si);
        emb[100 + t] = cosf(si);
    } else if (t < 102) {
        emb[100 + t] = 0.0f;
    }
    __syncthreads();
    if (t < GDP) {
        float g = 0.0f;
        if (t < DD) {
            float acc = b_pos[t];
            for (int k = 0; k < DD; ++k) acc += emb[k] * W_pos[k * DD + t];
            g = 2.0f / (1.0f + expf(-acc));
        }
        union { __half h; unsigned short s; } u;
        u.h = __float2half_rn(g);
        gat[p * GDP + t] = u.s;   // fp16; zeros at 202,203
    }
}

// ---------------- W_transform (202x1212 fp32) -> Bt (1280x224 bf16, transposed, padded)
__global__ void convB_kernel(const float* __restrict__ W, unsigned short* __restrict__ Bt) {
    int id = blockIdx.x * 256 + threadIdx.x;
    if (id >= NP * KP) return;
    int n = id / KP, k = id % KP;
    float v = (k < KK && n < DE) ? W[(size_t)k * DE + n] : 0.0f;
    Bt[id] = f2b(v);
}

// ---------------- node_states (100000x202 fp32) -> Abf (100096x224 bf16, padded)
__global__ void convA_kernel(const float* __restrict__ A, unsigned short* __restrict__ Abf) {
    int id = blockIdx.x * 256 + threadIdx.x;         // one bf16 pair per thread
    if (id >= NNP * (KP / 2)) return;
    int row = id / (KP / 2), kp = (id % (KP / 2)) * 2;
    float2 v = make_float2(0.0f, 0.0f);
    if (row < NN && kp < KK) v = *(const float2*)&A[(size_t)row * KK + kp]; // kp<=200 -> ok
    ushort2 o; o.x = f2b(v.x); o.y = f2b(v.y);
    *(ushort2*)&Abf[(size_t)row * KP + kp] = o;
}

// ---------------- prop = Abf @ Bt^T + b -> bf16[NN][PDE], MFMA 128x128 tile
// 2-phase double-buffered K-loop with counted vmcnt (catalog T3/T4-minimal).
// Old loop was stage -> syncthreads(vmcnt(0) drain) -> compute: every K-step ate
// a full HBM latency. Now: issue stage(k+1) at loop top, wait vmcnt(4) (= stage k
// done, stage k+1 still in flight), raw s_barriers; steady state never drains.
// LDS: sA/sB double-buffered (32 KB); epilogue sE aliases dead sA.
__global__ __launch_bounds__(256) void gemm_mfma(const unsigned short* __restrict__ Abf,
                                                 const unsigned short* __restrict__ Bt,
                                                 const float* __restrict__ bias,
                                                 unsigned short* __restrict__ C) {
    __shared__ unsigned short lds[16384];    // 32 KB
    unsigned short* sA = lds;                // [2][4096] (128 rows x 32 k per buf)
    unsigned short* sB = lds + 8192;         // [2][4096]
    unsigned short* sE = lds;                // epilogue alias (safe after final barrier)

    int t    = threadIdx.x;
    int lane = t & 63;
    int wave = t >> 6;
    int q    = lane >> 4;
    int r16  = lane & 15;
    int wm   = (wave >> 1) * 64;
    int wn   = (wave & 1) * 64;
    int row0 = blockIdx.y * 128;
    int col0 = blockIdx.x * 128;

    // staging geometry: lane covers 16B; rows wave*32+i*16+lrow; chunk XOR-swizzled
    int lrow = lane >> 2;
    int gch  = (lane & 3) ^ ((lrow >> 1) & 3);     // global k-chunk this lane fetches
    const unsigned short* aS0 = Abf + (size_t)(row0 + wave * 32 + lrow) * KP + gch * 8;
    const unsigned short* aS1 = aS0 + 16 * KP;
    const unsigned short* bS0 = Bt  + (size_t)(col0 + wave * 32 + lrow) * KP + gch * 8;
    const unsigned short* bS1 = bS0 + 16 * KP;

#define STAGE(b, kc) do {                                   \
        glds16(aS0 + (kc), &sA[(b)*4096 + wave*1024]);      \
        glds16(aS1 + (kc), &sA[(b)*4096 + wave*1024+512]);  \
        glds16(bS0 + (kc), &sB[(b)*4096 + wave*1024]);      \
        glds16(bS1 + (kc), &sB[(b)*4096 + wave*1024+512]);  \
    } while (0)

    f32x4 acc[4][4] = {};
    int swzr = (r16 >> 1) & 3;

    STAGE(0, 0);
    for (int k = 0; k < 7; ++k) {
        int cur = k & 1;
        if (k < 6) {
            STAGE(cur ^ 1, (k + 1) * 32);                       // 4 more in flight
            asm volatile("s_waitcnt vmcnt(4)" ::: "memory");    // stage k landed
        } else {
            asm volatile("s_waitcnt vmcnt(0)" ::: "memory");
        }
        __builtin_amdgcn_s_barrier();      // all waves' stage-k visible

        bf16x8 a[4], b[4];
        int sbase = cur * 4096;
        #pragma unroll
        for (int mi = 0; mi < 4; ++mi)
            a[mi] = *(const bf16x8*)&sA[sbase + (wm + mi * 16 + r16) * 32 + (q ^ swzr) * 8];
        #pragma unroll
        for (int ni = 0; ni < 4; ++ni)
            b[ni] = *(const bf16x8*)&sB[sbase + (wn + ni * 16 + r16) * 32 + (q ^ swzr) * 8];
        #pragma unroll
        for (int mi = 0; mi < 4; ++mi)
            #pragma unroll
            for (int ni = 0; ni < 4; ++ni)
                acc[mi][ni] = __builtin_amdgcn_mfma_f32_16x16x32_bf16(a[mi], b[ni], acc[mi][ni], 0, 0, 0);

        // reads of buf 'cur' retired (consumed by MFMA); barrier before next
        // iteration's STAGE overwrites it
        __builtin_amdgcn_s_barrier();
    }
#undef STAGE

    // epilogue: per-wave-private LDS staging -> 16B/lane aligned stores
    float bb[4];
    #pragma unroll
    for (int ni = 0; ni < 4; ++ni) {
        int col = col0 + wn + ni * 16 + r16;
        bb[ni] = (col < DE) ? bias[col] : 0.0f;
    }
    int epi = wave * 1152;            // 16 rows * 72
    int rl = lane >> 3, ck = lane & 7;
    #pragma unroll
    for (int mi = 0; mi < 4; ++mi) {
        #pragma unroll
        for (int ni = 0; ni < 4; ++ni)
            #pragma unroll
            for (int ri = 0; ri < 4; ++ri)
                sE[epi + (q * 4 + ri) * 72 + ni * 16 + r16] = f2b(acc[mi][ni][ri] + bb[ni]);
        #pragma unroll
        for (int ii = 0; ii < 2; ++ii) {
            int rr = ii * 8 + rl;
            bf16x8 v = *(const bf16x8*)&sE[epi + rr * 72 + ck * 8];
            int grow = row0 + wm + mi * 16 + rr;
            int gcol = col0 + wn + ck * 8;
            if (grow < NN && gcol < PDE)
                *(bf16x8*)&C[(size_t)grow * PDE + gcol] = v;
        }
    }
}

// ---------------- pass 1: histogram of targets
__global__ __launch_bounds__(256) void count_kernel(const int* __restrict__ edges,
                                                    int* __restrict__ count) {
    int i = blockIdx.x * 256 + threadIdx.x;
    if (i >= NE) return;
    atomicAdd(&count[edges[2 * i + 1]], 1);
}

// ---------------- pass 2: segment allocation (block scan + 1 atomic/block)
__global__ __launch_bounds__(256) void alloc_kernel(const int* __restrict__ count,
                                                    int* __restrict__ start,
                                                    int* __restrict__ cursor) {
    int t = blockIdx.x * 256 + threadIdx.x;
    int c = (t < NN) ? count[t] : 0;
    __shared__ int s[256];
    __shared__ int base;
    s[threadIdx.x] = c;
    __syncthreads();
    int v = c;
    for (int off = 1; off < 256; off <<= 1) {
        int u = (threadIdx.x >= off) ? s[threadIdx.x - off] : 0;
        __syncthreads();
        v += u;
        s[threadIdx.x] = v;
        __syncthreads();
    }
    if (threadIdx.x == 255) base = atomicAdd(cursor, v);
    __syncthreads();
    if (t < NN) start[t] = base + v - c;
}

// ---------------- pass 3: scatter PACKED edge records (start becomes segment END)
// record: src (17b) | e (3b) | pos (9b)
__global__ __launch_bounds__(256) void scatter_kernel(const int* __restrict__ edges,
                                                      const int* __restrict__ pos_lists,
                                                      int* __restrict__ start,
                                                      unsigned* __restrict__ recs) {
    int i = blockIdx.x * 256 + threadIdx.x;
    if (i >= NE) return;
    int2 st = *(const int2*)&edges[2 * i];              // (src, tgt), 8B aligned
    int e = (int)((unsigned)i / MM);                    // edge type
    unsigned rec = (unsigned)st.x | ((unsigned)e << 17) | ((unsigned)pos_lists[i] << 20);
    int p = atomicAdd(&start[st.y], 1);
    recs[p] = rec;
}

// ---------------- pass 4: round-1/2 structure (best measured: 168 us) + fp16
// gating (numerics verified round-4: absmax unchanged). Round-4 proved deep MLP
// does NOT help (random-granule read path limits at ~2.4-2.8 TB/s), so the
// simple register pipeline is the right shape.
__global__ __launch_bounds__(256) void gather_kernel(const unsigned short* __restrict__ prop,
                                                     const unsigned short* __restrict__ gat,
                                                     const int* __restrict__ count,
                                                     const int* __restrict__ seg_end,
                                                     const unsigned* __restrict__ recs,
                                                     float* __restrict__ out) {
    int wid = blockIdx.x * 4 + (threadIdx.x >> 6);
    if (wid >= NN) return;
    int lane = threadIdx.x & 63;
    int c = count[wid];
    int end = seg_end[wid];
    int begin = end - c;
    int d = lane * 4;
    bool act = d < DD;                    // lanes 0..50
    float a0 = 0.f, a1 = 0.f, a2 = 0.f, a3 = 0.f;

    for (int base = begin; base < end; base += 64) {
        int n = end - base; if (n > 64) n = 64;
        unsigned rec = 0u;
        if (lane < n) rec = recs[base + lane];
        int poff = (int)(rec & 0x1FFFFu) * PDE + (int)((rec >> 17) & 7u) * DD;  // elems
        int goff = (int)(rec >> 20) * GDP;                                      // elems

        for (int jj = 0; jj < n; jj += 4) {
            int po[4], go[4];
            #pragma unroll
            for (int u = 0; u < 4; ++u) {
                int j = jj + u; if (j >= n) j = jj;     // clamped dups: L1-hit, unused
                po[u] = __shfl(poff, j);
                go[u] = __shfl(goff, j);
            }
            uint2 pv[4], gv[4];
            #pragma unroll
            for (int u = 0; u < 4; ++u) {
                pv[u] = make_uint2(0u, 0u);
                gv[u] = make_uint2(0u, 0u);
                if (act) {
                    pv[u] = *(const uint2*)&prop[po[u] + d];
                    gv[u] = *(const uint2*)&gat[go[u] + d];
                }
            }
            #pragma unroll
            for (int u = 0; u < 4; ++u) {
                if (jj + u < n || u == 0) {             // n wave-uniform: scalar branch
                    float2 g01 = __half22float2(*(const __half2*)&gv[u].x);
                    float2 g23 = __half22float2(*(const __half2*)&gv[u].y);
                    a0 += __uint_as_float(pv[u].x << 16)         * g01.x;
                    a1 += __uint_as_float(pv[u].x & 0xffff0000u) * g01.y;
                    a2 += __uint_as_float(pv[u].y << 16)         * g23.x;
                    a3 += __uint_as_float(pv[u].y & 0xffff0000u) * g23.y;
                }
            }
        }
    }

    float div = (c == 0 ? 1.0f : (float)c) + 1e-8f;
    float inv = 1.0f / div;
    if (act) {
        float* orow = out + (size_t)wid * DD;
        *(float2*)&orow[d] = make_float2(a0 * inv, a1 * inv);
        if (d + 2 < DD) *(float2*)&orow[d + 2] = make_float2(a2 * inv, a3 * inv);
    }
}

extern "C" void kernel_launch(void* const* d_in, const int* in_sizes, int n_in,
                              void* d_out, int out_size, void* d_ws, size_t ws_size,
                              hipStream_t stream) {
    const float* node_states = (const float*)d_in[0];
    const int*   edges       = (const int*)d_in[1];
    const int*   pos_lists   = (const int*)d_in[2];
    const float* W_transform = (const float*)d_in[3];
    const float* b_transform = (const float*)d_in[4];
    const float* W_pos       = (const float*)d_in[5];
    const float* b_pos       = (const float*)d_in[6];
    float* out = (float*)d_out;

    // workspace layout (16B-aligned blocks)
    char* ws = (char*)d_ws;
    unsigned short* gat = (unsigned short*)ws;  ws += (size_t)NPOS * GDP * 2;  // 208,896 B
    int* count  = (int*)ws;                     ws += (size_t)NN * 4;          // 400,000 B
    int* start  = (int*)ws;                     ws += (size_t)NN * 4;          // 400,000 B
    int* cursor = (int*)ws;                     ws += 16;
    unsigned short* Bt  = (unsigned short*)ws;  ws += (size_t)NP * KP * 2;     // 573,440 B
    unsigned short* Abf = (unsigned short*)ws;  ws += (size_t)NNP * KP * 2;    // 44,843,008 B
    unsigned* recs = (unsigned*)ws;             ws += (size_t)NE * 4;          // 4,800,000 B
    unsigned short* prop = (unsigned short*)ws;                                // 243,200,000 B

    hipMemsetAsync(count, 0, NN * sizeof(int), stream);
    hipMemsetAsync(cursor, 0, sizeof(int), stream);

    gating_kernel<<<NPOS, 256, 0, stream>>>(W_pos, b_pos, gat);
    convB_kernel<<<(NP * KP + 255) / 256, 256, 0, stream>>>(W_transform, Bt);
    convA_kernel<<<(NNP * (KP / 2) + 255) / 256, 256, 0, stream>>>(node_states, Abf);

    dim3 g2(NP / 128, NNP / 128);
    gemm_mfma<<<g2, 256, 0, stream>>>(Abf, Bt, b_transform, prop);

    count_kernel<<<(NE + 255) / 256, 256, 0, stream>>>(edges, count);
    alloc_kernel<<<(NN + 255) / 256, 256, 0, stream>>>(count, start, cursor);
    scatter_kernel<<<(NE + 255) / 256, 256, 0, stream>>>(edges, pos_lists, start, recs);
    gather_kernel<<<(NN + 3) / 4, 256, 0, stream>>>(prop, gat, count, start, recs, out);
}

// Round 7
// 532.704 us; speedup vs baseline: 1.2334x; 1.1860x over previous
//
#include <hip/hip_runtime.h>
#include <hip/hip_bf16.h>
#include <hip/hip_fp16.h>
#include <math.h>

#define NN   100000   // nodes
#define NNP  100096   // nodes padded to mult of 128 (GEMM staging reads, zero-filled)
#define DD   202      // feature dim
#define ET   6        // edge types
#define MM   200000   // edges per type
#define NE   (ET*MM)  // 1.2M edges
#define NPOS 512
#define GDP  204      // gating row stride (fp16 elements; 408-B rows, zeros at 202..203)
#define DE   1212     // DD*ET
#define PDE  1216     // prop row stride (padded; 2432 B rows -> 16B-aligned, 64B-aligned)
#define KK   202      // GEMM K
#define KP   224      // K padded to 7*32
#define NP   1280     // N padded to 10*128

// fused_prep geometry: [0,512)=gating | [512,1632)=convB | then 1564 groups of
// (7 convA + 3 count).  convB blocks = NP*KP/256 = 1120 (exact).
// convA blocks = NNP*(KP/8)/256 = 10948 (exact, 8 halves/thread).
// count blocks = NE/256 = 4688.
#define NB_CONVB 1120
#define NB_CA    10948
#define PREPG    1564       // 1564*7 = 10948 convA ids (exact); 1564*3 = 4692 >= 4688 count ids
// fused_main geometry: 1564 groups of (5 gemm + 3 scatter).
// gemm wgs = (NP/128)*(NNP/128) = 10*782 = 7820 = 1564*5 (exact); scatter ids 4692 >= 4688.
#define MAING    1564

typedef __attribute__((ext_vector_type(8))) short bf16x8;
typedef __attribute__((ext_vector_type(4))) float f32x4;

static __device__ inline unsigned short f2b(float f) {
    union { __hip_bfloat16 h; unsigned short s; } u;
    u.h = __float2bfloat16(f);
    return u.s;
}

static __device__ inline void glds16(const unsigned short* g, unsigned short* l) {
    __builtin_amdgcn_global_load_lds(
        (const __attribute__((address_space(1))) unsigned int*)g,
        (__attribute__((address_space(3))) unsigned int*)l, 16, 0, 0);
}

// ---------------- fused prep: gating | convB | convA (vectorized) | count
// All four are mutually independent; count (atomic-latency-bound) is
// interleaved 7:3 with convA (BW-bound) so its latency hides.
__global__ __launch_bounds__(256) void fused_prep(const float* __restrict__ W_pos,
                                                  const float* __restrict__ b_pos,
                                                  unsigned short* __restrict__ gat,
                                                  const float* __restrict__ W,
                                                  unsigned short* __restrict__ Bt,
                                                  const float* __restrict__ A,
                                                  unsigned short* __restrict__ Abf,
                                                  const int* __restrict__ edges,
                                                  int* __restrict__ count) {
    __shared__ float emb[DD];
    int bid = blockIdx.x;
    int t = threadIdx.x;

    if (bid < NPOS) {
        // ---- pos_gating: (512 x GDP) fp16 = 2*sigmoid(pos_embs @ W_pos + b_pos)
        int p = bid;
        if (t < 100) {
            float invf = expf(-((float)t / 100.0f) * 9.210340371976184f); // ln(10000)
            float si = (float)p * invf;
            emb[t]       = sinf(si);
            emb[100 + t] = cosf(si);
        } else if (t < 102) {
            emb[100 + t] = 0.0f;
        }
        __syncthreads();
        if (t < GDP) {
            float g = 0.0f;
            if (t < DD) {
                float acc = b_pos[t];
                for (int k = 0; k < DD; ++k) acc += emb[k] * W_pos[k * DD + t];
                g = 2.0f / (1.0f + expf(-acc));
            }
            union { __half h; unsigned short s; } u;
            u.h = __float2half_rn(g);
            gat[p * GDP + t] = u.s;   // fp16; zeros at 202,203
        }
        return;
    }
    bid -= NPOS;

    if (bid < NB_CONVB) {
        // ---- W_transform (202x1212 fp32) -> Bt (1280x224 bf16, transposed, padded)
        int id = bid * 256 + t;            // < NP*KP exactly
        int n = id / KP, k = id % KP;
        float v = (k < KK && n < DE) ? W[(size_t)k * DE + n] : 0.0f;
        Bt[id] = f2b(v);
        return;
    }
    bid -= NB_CONVB;

    int g = bid / 10, s = bid % 10;
    if (s < 7) {
        // ---- convA: node_states (100000x202 fp32) -> Abf (100096x224 bf16)
        // 8 halves per thread; float2 loads (A rows are 8B-aligned, not 16B).
        int ca = g * 7 + s;                // < NB_CA exactly
        int id = ca * 256 + t;             // < NNP*28
        int row = id / 28;
        int kp  = (id % 28) * 8;
        bf16x8 o;
        #pragma unroll
        for (int j = 0; j < 8; ++j) o[j] = 0;
        if (row < NN) {
            const float* ar = A + (size_t)row * KK;
            #pragma unroll
            for (int j = 0; j < 4; ++j) {
                if (kp + 2 * j + 1 < KK) {           // KK even: pairs never straddle
                    float2 v = *(const float2*)&ar[kp + 2 * j];
                    o[2 * j]     = (short)f2b(v.x);
                    o[2 * j + 1] = (short)f2b(v.y);
                }
            }
        }
        *(bf16x8*)&Abf[(size_t)row * KP + kp] = o;   // 16B-aligned
    } else {
        // ---- count: histogram of targets
        int cid = g * 3 + (s - 7);
        int i = cid * 256 + t;
        if (i < NE) atomicAdd(&count[edges[2 * i + 1]], 1);
    }
}

// ---------------- pass 2: segment allocation (block scan + 1 atomic/block)
__global__ __launch_bounds__(256) void alloc_kernel(const int* __restrict__ count,
                                                    int* __restrict__ start,
                                                    int* __restrict__ cursor) {
    int t = blockIdx.x * 256 + threadIdx.x;
    int c = (t < NN) ? count[t] : 0;
    __shared__ int s[256];
    __shared__ int base;
    s[threadIdx.x] = c;
    __syncthreads();
    int v = c;
    for (int off = 1; off < 256; off <<= 1) {
        int u = (threadIdx.x >= off) ? s[threadIdx.x - off] : 0;
        __syncthreads();
        v += u;
        s[threadIdx.x] = v;
        __syncthreads();
    }
    if (threadIdx.x == 255) base = atomicAdd(cursor, v);
    __syncthreads();
    if (t < NN) start[t] = base + v - c;
}

// ---------------- fused main: gemm (MFMA 128x128, 2-phase counted vmcnt) |
// scatter (packed records).  Independent; scatter's atomic-return latency
// hides under the GEMM's compute.  Interleave 5:3, groups of 8.
__global__ __launch_bounds__(256) void fused_main(const unsigned short* __restrict__ Abf,
                                                  const unsigned short* __restrict__ Bt,
                                                  const float* __restrict__ bias,
                                                  unsigned short* __restrict__ C,
                                                  const int* __restrict__ edges,
                                                  const int* __restrict__ pos_lists,
                                                  int* __restrict__ start,
                                                  unsigned* __restrict__ recs) {
    __shared__ unsigned short lds[16384];    // 32 KB (gemm branch only)
    int grp = blockIdx.x >> 3, sl = blockIdx.x & 7;

    if (sl >= 5) {
        // ---- scatter PACKED edge records: src(17b) | e(3b) | pos(9b)
        int sid = grp * 3 + (sl - 5);
        int i = sid * 256 + threadIdx.x;
        if (i < NE) {
            int2 st = *(const int2*)&edges[2 * i];
            int e = (int)((unsigned)i / MM);
            unsigned rec = (unsigned)st.x | ((unsigned)e << 17) | ((unsigned)pos_lists[i] << 20);
            int p = atomicAdd(&start[st.y], 1);
            recs[p] = rec;
        }
        return;
    }

    // ---- gemm: prop = Abf @ Bt^T + b -> bf16[NN][PDE]
    int wg = grp * 5 + sl;                  // 0..7819 exactly
    unsigned short* sA = lds;               // [2][4096] (128 rows x 32 k per buf)
    unsigned short* sB = lds + 8192;        // [2][4096]
    unsigned short* sE = lds;               // epilogue alias (safe after final barrier)

    int t    = threadIdx.x;
    int lane = t & 63;
    int wave = t >> 6;
    int q    = lane >> 4;
    int r16  = lane & 15;
    int wm   = (wave >> 1) * 64;
    int wn   = (wave & 1) * 64;
    int row0 = (wg / 10) * 128;
    int col0 = (wg % 10) * 128;

    // staging geometry: lane covers 16B; rows wave*32+i*16+lrow; chunk XOR-swizzled
    int lrow = lane >> 2;
    int gch  = (lane & 3) ^ ((lrow >> 1) & 3);
    const unsigned short* aS0 = Abf + (size_t)(row0 + wave * 32 + lrow) * KP + gch * 8;
    const unsigned short* aS1 = aS0 + 16 * KP;
    const unsigned short* bS0 = Bt  + (size_t)(col0 + wave * 32 + lrow) * KP + gch * 8;
    const unsigned short* bS1 = bS0 + 16 * KP;

#define STAGE(b, kc) do {                                   \
        glds16(aS0 + (kc), &sA[(b)*4096 + wave*1024]);      \
        glds16(aS1 + (kc), &sA[(b)*4096 + wave*1024+512]);  \
        glds16(bS0 + (kc), &sB[(b)*4096 + wave*1024]);      \
        glds16(bS1 + (kc), &sB[(b)*4096 + wave*1024+512]);  \
    } while (0)

    f32x4 acc[4][4] = {};
    int swzr = (r16 >> 1) & 3;

    STAGE(0, 0);
    for (int k = 0; k < 7; ++k) {
        int cur = k & 1;
        if (k < 6) {
            STAGE(cur ^ 1, (k + 1) * 32);                       // 4 more in flight
            asm volatile("s_waitcnt vmcnt(4)" ::: "memory");    // stage k landed
        } else {
            asm volatile("s_waitcnt vmcnt(0)" ::: "memory");
        }
        __builtin_amdgcn_s_barrier();      // all waves' stage-k visible

        bf16x8 a[4], b[4];
        int sbase = cur * 4096;
        #pragma unroll
        for (int mi = 0; mi < 4; ++mi)
            a[mi] = *(const bf16x8*)&sA[sbase + (wm + mi * 16 + r16) * 32 + (q ^ swzr) * 8];
        #pragma unroll
        for (int ni = 0; ni < 4; ++ni)
            b[ni] = *(const bf16x8*)&sB[sbase + (wn + ni * 16 + r16) * 32 + (q ^ swzr) * 8];
        #pragma unroll
        for (int mi = 0; mi < 4; ++mi)
            #pragma unroll
            for (int ni = 0; ni < 4; ++ni)
                acc[mi][ni] = __builtin_amdgcn_mfma_f32_16x16x32_bf16(a[mi], b[ni], acc[mi][ni], 0, 0, 0);

        __builtin_amdgcn_s_barrier();      // buf 'cur' reads retired before overwrite
    }
#undef STAGE

    // epilogue: per-wave-private LDS staging -> 16B/lane aligned stores
    float bb[4];
    #pragma unroll
    for (int ni = 0; ni < 4; ++ni) {
        int col = col0 + wn + ni * 16 + r16;
        bb[ni] = (col < DE) ? bias[col] : 0.0f;
    }
    int epi = wave * 1152;            // 16 rows * 72
    int rl = lane >> 3, ck = lane & 7;
    #pragma unroll
    for (int mi = 0; mi < 4; ++mi) {
        #pragma unroll
        for (int ni = 0; ni < 4; ++ni)
            #pragma unroll
            for (int ri = 0; ri < 4; ++ri)
                sE[epi + (q * 4 + ri) * 72 + ni * 16 + r16] = f2b(acc[mi][ni][ri] + bb[ni]);
        #pragma unroll
        for (int ii = 0; ii < 2; ++ii) {
            int rr = ii * 8 + rl;
            bf16x8 v = *(const bf16x8*)&sE[epi + rr * 72 + ck * 8];
            int grow = row0 + wm + mi * 16 + rr;
            int gcol = col0 + wn + ck * 8;
            if (grow < NN && gcol < PDE)
                *(bf16x8*)&C[(size_t)grow * PDE + gcol] = v;
        }
    }
}

// ---------------- gather: one wave per target, round-1/2 structure (best
// measured) + fp16 gating.  Deep MLP proven unhelpful (round 4): the random
// 408-B-granule read path limits at ~2.4-2.8 TB/s.
__global__ __launch_bounds__(256) void gather_kernel(const unsigned short* __restrict__ prop,
                                                     const unsigned short* __restrict__ gat,
                                                     const int* __restrict__ count,
                                                     const int* __restrict__ seg_end,
                                                     const unsigned* __restrict__ recs,
                                                     float* __restrict__ out) {
    int wid = blockIdx.x * 4 + (threadIdx.x >> 6);
    if (wid >= NN) return;
    int lane = threadIdx.x & 63;
    int c = count[wid];
    int end = seg_end[wid];
    int begin = end - c;
    int d = lane * 4;
    bool act = d < DD;                    // lanes 0..50
    float a0 = 0.f, a1 = 0.f, a2 = 0.f, a3 = 0.f;

    for (int base = begin; base < end; base += 64) {
        int n = end - base; if (n > 64) n = 64;
        unsigned rec = 0u;
        if (lane < n) rec = recs[base + lane];
        int poff = (int)(rec & 0x1FFFFu) * PDE + (int)((rec >> 17) & 7u) * DD;  // elems
        int goff = (int)(rec >> 20) * GDP;                                      // elems

        for (int jj = 0; jj < n; jj += 4) {
            int po[4], go[4];
            #pragma unroll
            for (int u = 0; u < 4; ++u) {
                int j = jj + u; if (j >= n) j = jj;     // clamped dups: L1-hit, unused
                po[u] = __shfl(poff, j);
                go[u] = __shfl(goff, j);
            }
            uint2 pv[4], gv[4];
            #pragma unroll
            for (int u = 0; u < 4; ++u) {
                pv[u] = make_uint2(0u, 0u);
                gv[u] = make_uint2(0u, 0u);
                if (act) {
                    pv[u] = *(const uint2*)&prop[po[u] + d];
                    gv[u] = *(const uint2*)&gat[go[u] + d];
                }
            }
            #pragma unroll
            for (int u = 0; u < 4; ++u) {
                if (jj + u < n || u == 0) {             // n wave-uniform: scalar branch
                    float2 g01 = __half22float2(*(const __half2*)&gv[u].x);
                    float2 g23 = __half22float2(*(const __half2*)&gv[u].y);
                    a0 += __uint_as_float(pv[u].x << 16)         * g01.x;
                    a1 += __uint_as_float(pv[u].x & 0xffff0000u) * g01.y;
                    a2 += __uint_as_float(pv[u].y << 16)         * g23.x;
                    a3 += __uint_as_float(pv[u].y & 0xffff0000u) * g23.y;
                }
            }
        }
    }

    float div = (c == 0 ? 1.0f : (float)c) + 1e-8f;
    float inv = 1.0f / div;
    if (act) {
        float* orow = out + (size_t)wid * DD;
        *(float2*)&orow[d] = make_float2(a0 * inv, a1 * inv);
        if (d + 2 < DD) *(float2*)&orow[d + 2] = make_float2(a2 * inv, a3 * inv);
    }
}

extern "C" void kernel_launch(void* const* d_in, const int* in_sizes, int n_in,
                              void* d_out, int out_size, void* d_ws, size_t ws_size,
                              hipStream_t stream) {
    const float* node_states = (const float*)d_in[0];
    const int*   edges       = (const int*)d_in[1];
    const int*   pos_lists   = (const int*)d_in[2];
    const float* W_transform = (const float*)d_in[3];
    const float* b_transform = (const float*)d_in[4];
    const float* W_pos       = (const float*)d_in[5];
    const float* b_pos       = (const float*)d_in[6];
    float* out = (float*)d_out;

    // workspace layout (16B-aligned blocks)
    char* ws = (char*)d_ws;
    unsigned short* gat = (unsigned short*)ws;  ws += (size_t)NPOS * GDP * 2;  // 208,896 B
    int* count  = (int*)ws;                     ws += (size_t)NN * 4;          // 400,000 B
    int* start  = (int*)ws;                     ws += (size_t)NN * 4;          // 400,000 B
    int* cursor = (int*)ws;                     ws += 16;
    unsigned short* Bt  = (unsigned short*)ws;  ws += (size_t)NP * KP * 2;     // 573,440 B
    unsigned short* Abf = (unsigned short*)ws;  ws += (size_t)NNP * KP * 2;    // 44,843,008 B
    unsigned* recs = (unsigned*)ws;             ws += (size_t)NE * 4;          // 4,800,000 B
    unsigned short* prop = (unsigned short*)ws;                                // 243,200,000 B

    hipMemsetAsync(count, 0, NN * sizeof(int), stream);
    hipMemsetAsync(cursor, 0, sizeof(int), stream);

    // 1. gating | convB | convA | count   (independent; count hidden under convA)
    fused_prep<<<NPOS + NB_CONVB + PREPG * 10, 256, 0, stream>>>(
        W_pos, b_pos, gat, W_transform, Bt, node_states, Abf, edges, count);

    // 2. segment allocation (needs count)
    alloc_kernel<<<(NN + 255) / 256, 256, 0, stream>>>(count, start, cursor);

    // 3. gemm | scatter   (independent; scatter hidden under gemm)
    fused_main<<<MAING * 8, 256, 0, stream>>>(
        Abf, Bt, b_transform, prop, edges, pos_lists, start, recs);

    // 4. gather (needs everything)
    gather_kernel<<<(NN + 3) / 4, 256, 0, stream>>>(prop, gat, count, start, recs, out);
}

// Round 8
// 531.872 us; speedup vs baseline: 1.2353x; 1.0016x over previous
//
#include <hip/hip_runtime.h>
#include <hip/hip_bf16.h>
#include <hip/hip_fp16.h>
#include <math.h>

#define NN   100000   // nodes
#define NNP  100096   // nodes padded to mult of 128 (GEMM staging reads, zero-filled)
#define DD   202      // feature dim
#define ET   6        // edge types
#define MM   200000   // edges per type
#define NE   (ET*MM)  // 1.2M edges
#define NPOS 512
#define GDP  204      // gating row stride (fp16 elements; 408-B rows, zeros at 202..203)
#define DE   1212     // DD*ET
#define PDE  1216     // prop row stride (padded; 2432 B rows -> 16B-aligned, 64B-aligned)
#define KK   202      // GEMM K
#define KP   224      // K padded to 7*32
#define NP   1280     // N padded to 10*128

// fused_prep geometry: [0,512)=gating | [512,1632)=convB | then 1564 groups of
// (7 convA + 3 count).  Period 10 vs 8 XCDs -> every XCD gets both work types.
#define NB_CONVB 1120
#define NB_CA    10948
#define PREPG    1564
// fused_main geometry: CONCATENATED (round-7 post-mortem: the old 8-slot
// grouping pinned GEMM to XCDs 0-4 and left XCDs 5-7 idle -> occupancy 22%).
// [0, GEMM_WGS) = gemm, [GEMM_WGS, +NB_SCAT) = scatter.
#define GEMM_WGS 7820     // (NP/128)*(NNP/128) = 10*782
#define NB_SCAT  4688     // ceil(NE/256)

typedef __attribute__((ext_vector_type(8))) short bf16x8;
typedef __attribute__((ext_vector_type(4))) float f32x4;

static __device__ inline unsigned short f2b(float f) {
    union { __hip_bfloat16 h; unsigned short s; } u;
    u.h = __float2bfloat16(f);
    return u.s;
}

static __device__ inline void glds16(const unsigned short* g, unsigned short* l) {
    __builtin_amdgcn_global_load_lds(
        (const __attribute__((address_space(1))) unsigned int*)g,
        (__attribute__((address_space(3))) unsigned int*)l, 16, 0, 0);
}

// ---------------- fused prep: gating | convB | convA (vectorized) | count
__global__ __launch_bounds__(256) void fused_prep(const float* __restrict__ W_pos,
                                                  const float* __restrict__ b_pos,
                                                  unsigned short* __restrict__ gat,
                                                  const float* __restrict__ W,
                                                  unsigned short* __restrict__ Bt,
                                                  const float* __restrict__ A,
                                                  unsigned short* __restrict__ Abf,
                                                  const int* __restrict__ edges,
                                                  int* __restrict__ count) {
    __shared__ float emb[DD];
    int bid = blockIdx.x;
    int t = threadIdx.x;

    if (bid < NPOS) {
        // ---- pos_gating: (512 x GDP) fp16 = 2*sigmoid(pos_embs @ W_pos + b_pos)
        int p = bid;
        if (t < 100) {
            float invf = expf(-((float)t / 100.0f) * 9.210340371976184f); // ln(10000)
            float si = (float)p * invf;
            emb[t]       = sinf(si);
            emb[100 + t] = cosf(si);
        } else if (t < 102) {
            emb[100 + t] = 0.0f;
        }
        __syncthreads();
        if (t < GDP) {
            float g = 0.0f;
            if (t < DD) {
                float acc = b_pos[t];
                for (int k = 0; k < DD; ++k) acc += emb[k] * W_pos[k * DD + t];
                g = 2.0f / (1.0f + expf(-acc));
            }
            union { __half h; unsigned short s; } u;
            u.h = __float2half_rn(g);
            gat[p * GDP + t] = u.s;   // fp16; zeros at 202,203
        }
        return;
    }
    bid -= NPOS;

    if (bid < NB_CONVB) {
        // ---- W_transform (202x1212 fp32) -> Bt (1280x224 bf16, transposed, padded)
        int id = bid * 256 + t;            // < NP*KP exactly
        int n = id / KP, k = id % KP;
        float v = (k < KK && n < DE) ? W[(size_t)k * DE + n] : 0.0f;
        Bt[id] = f2b(v);
        return;
    }
    bid -= NB_CONVB;

    int g = bid / 10, s = bid % 10;
    if (s < 7) {
        // ---- convA: node_states (100000x202 fp32) -> Abf (100096x224 bf16)
        int ca = g * 7 + s;                // < NB_CA exactly
        int id = ca * 256 + t;             // < NNP*28
        int row = id / 28;
        int kp  = (id % 28) * 8;
        bf16x8 o;
        #pragma unroll
        for (int j = 0; j < 8; ++j) o[j] = 0;
        if (row < NN) {
            const float* ar = A + (size_t)row * KK;
            #pragma unroll
            for (int j = 0; j < 4; ++j) {
                if (kp + 2 * j + 1 < KK) {           // KK even: pairs never straddle
                    float2 v = *(const float2*)&ar[kp + 2 * j];
                    o[2 * j]     = (short)f2b(v.x);
                    o[2 * j + 1] = (short)f2b(v.y);
                }
            }
        }
        *(bf16x8*)&Abf[(size_t)row * KP + kp] = o;   // 16B-aligned
    } else {
        // ---- count: histogram of targets
        int cid = g * 3 + (s - 7);
        int i = cid * 256 + t;
        if (i < NE) atomicAdd(&count[edges[2 * i + 1]], 1);
    }
}

// ---------------- pass 2: segment allocation (block scan + 1 atomic/block)
__global__ __launch_bounds__(256) void alloc_kernel(const int* __restrict__ count,
                                                    int* __restrict__ start,
                                                    int* __restrict__ cursor) {
    int t = blockIdx.x * 256 + threadIdx.x;
    int c = (t < NN) ? count[t] : 0;
    __shared__ int s[256];
    __shared__ int base;
    s[threadIdx.x] = c;
    __syncthreads();
    int v = c;
    for (int off = 1; off < 256; off <<= 1) {
        int u = (threadIdx.x >= off) ? s[threadIdx.x - off] : 0;
        __syncthreads();
        v += u;
        s[threadIdx.x] = v;
        __syncthreads();
    }
    if (threadIdx.x == 255) base = atomicAdd(cursor, v);
    __syncthreads();
    if (t < NN) start[t] = base + v - c;
}

// ---------------- fused main: [0,GEMM_WGS) gemm | [GEMM_WGS,+NB_SCAT) scatter.
// Concatenated so both spread over all 8 XCDs (round-robin on blockIdx).
// GEMM wg additionally XCD-chunk swizzled (bijective, q=977 r=4) so the 10
// blocks sharing an A row-panel co-locate on ONE XCD -> A-staging is L2-hit;
// the 2-phase counted-vmcnt pipeline then fully covers staging latency.
__global__ __launch_bounds__(256) void fused_main(const unsigned short* __restrict__ Abf,
                                                  const unsigned short* __restrict__ Bt,
                                                  const float* __restrict__ bias,
                                                  unsigned short* __restrict__ C,
                                                  const int* __restrict__ edges,
                                                  const int* __restrict__ pos_lists,
                                                  int* __restrict__ start,
                                                  unsigned* __restrict__ recs) {
    __shared__ unsigned short lds[16384];    // 32 KB (gemm branch only)
    int b = blockIdx.x;

    if (b >= GEMM_WGS) {
        // ---- scatter PACKED edge records: src(17b) | e(3b) | pos(9b)
        int i = (b - GEMM_WGS) * 256 + threadIdx.x;
        if (i < NE) {
            int2 st = *(const int2*)&edges[2 * i];
            int e = (int)((unsigned)i / MM);
            unsigned rec = (unsigned)st.x | ((unsigned)e << 17) | ((unsigned)pos_lists[i] << 20);
            int p = atomicAdd(&start[st.y], 1);
            recs[p] = rec;
        }
        return;
    }

    // ---- gemm: prop = Abf @ Bt^T + b -> bf16[NN][PDE]
    // bijective XCD-chunk map: XCD x (= b%8) owns a contiguous lin-range.
    int x = b & 7, i0 = b >> 3;
    int lin = (x < 4) ? x * 978 + i0 : 3912 + (x - 4) * 977 + i0;
    int row0 = (lin / 10) * 128;
    int col0 = (lin % 10) * 128;

    unsigned short* sA = lds;               // [2][4096] (128 rows x 32 k per buf)
    unsigned short* sB = lds + 8192;        // [2][4096]
    unsigned short* sE = lds;               // epilogue alias (safe after final barrier)

    int t    = threadIdx.x;
    int lane = t & 63;
    int wave = t >> 6;
    int q    = lane >> 4;
    int r16  = lane & 15;
    int wm   = (wave >> 1) * 64;
    int wn   = (wave & 1) * 64;

    // staging geometry: lane covers 16B; rows wave*32+i*16+lrow; chunk XOR-swizzled
    int lrow = lane >> 2;
    int gch  = (lane & 3) ^ ((lrow >> 1) & 3);
    const unsigned short* aS0 = Abf + (size_t)(row0 + wave * 32 + lrow) * KP + gch * 8;
    const unsigned short* aS1 = aS0 + 16 * KP;
    const unsigned short* bS0 = Bt  + (size_t)(col0 + wave * 32 + lrow) * KP + gch * 8;
    const unsigned short* bS1 = bS0 + 16 * KP;

#define STAGE(bf, kc) do {                                   \
        glds16(aS0 + (kc), &sA[(bf)*4096 + wave*1024]);      \
        glds16(aS1 + (kc), &sA[(bf)*4096 + wave*1024+512]);  \
        glds16(bS0 + (kc), &sB[(bf)*4096 + wave*1024]);      \
        glds16(bS1 + (kc), &sB[(bf)*4096 + wave*1024+512]);  \
    } while (0)

    f32x4 acc[4][4] = {};
    int swzr = (r16 >> 1) & 3;

    STAGE(0, 0);
    for (int k = 0; k < 7; ++k) {
        int cur = k & 1;
        if (k < 6) {
            STAGE(cur ^ 1, (k + 1) * 32);                       // 4 more in flight
            asm volatile("s_waitcnt vmcnt(4)" ::: "memory");    // stage k landed
        } else {
            asm volatile("s_waitcnt vmcnt(0)" ::: "memory");
        }
        __builtin_amdgcn_s_barrier();      // all waves' stage-k visible

        bf16x8 a[4], bb2[4];
        int sbase = cur * 4096;
        #pragma unroll
        for (int mi = 0; mi < 4; ++mi)
            a[mi] = *(const bf16x8*)&sA[sbase + (wm + mi * 16 + r16) * 32 + (q ^ swzr) * 8];
        #pragma unroll
        for (int ni = 0; ni < 4; ++ni)
            bb2[ni] = *(const bf16x8*)&sB[sbase + (wn + ni * 16 + r16) * 32 + (q ^ swzr) * 8];
        #pragma unroll
        for (int mi = 0; mi < 4; ++mi)
            #pragma unroll
            for (int ni = 0; ni < 4; ++ni)
                acc[mi][ni] = __builtin_amdgcn_mfma_f32_16x16x32_bf16(a[mi], bb2[ni], acc[mi][ni], 0, 0, 0);

        __builtin_amdgcn_s_barrier();      // buf 'cur' reads retired before overwrite
    }
#undef STAGE

    // epilogue: per-wave-private LDS staging -> 16B/lane aligned stores
    float bb[4];
    #pragma unroll
    for (int ni = 0; ni < 4; ++ni) {
        int col = col0 + wn + ni * 16 + r16;
        bb[ni] = (col < DE) ? bias[col] : 0.0f;
    }
    int epi = wave * 1152;            // 16 rows * 72
    int rl = lane >> 3, ck = lane & 7;
    #pragma unroll
    for (int mi = 0; mi < 4; ++mi) {
        #pragma unroll
        for (int ni = 0; ni < 4; ++ni)
            #pragma unroll
            for (int ri = 0; ri < 4; ++ri)
                sE[epi + (q * 4 + ri) * 72 + ni * 16 + r16] = f2b(acc[mi][ni][ri] + bb[ni]);
        #pragma unroll
        for (int ii = 0; ii < 2; ++ii) {
            int rr = ii * 8 + rl;
            bf16x8 v = *(const bf16x8*)&sE[epi + rr * 72 + ck * 8];
            int grow = row0 + wm + mi * 16 + rr;
            int gcol = col0 + wn + ck * 8;
            if (grow < NN && gcol < PDE)
                *(bf16x8*)&C[(size_t)grow * PDE + gcol] = v;
        }
    }
}

// ---------------- gather: one wave per target, round-1/2 structure (best
// measured) + fp16 gating.  Deep MLP proven unhelpful (round 4): the random
// 408-B-granule read path limits at ~2.4-2.8 TB/s.
__global__ __launch_bounds__(256) void gather_kernel(const unsigned short* __restrict__ prop,
                                                     const unsigned short* __restrict__ gat,
                                                     const int* __restrict__ count,
                                                     const int* __restrict__ seg_end,
                                                     const unsigned* __restrict__ recs,
                                                     float* __restrict__ out) {
    int wid = blockIdx.x * 4 + (threadIdx.x >> 6);
    if (wid >= NN) return;
    int lane = threadIdx.x & 63;
    int c = count[wid];
    int end = seg_end[wid];
    int begin = end - c;
    int d = lane * 4;
    bool act = d < DD;                    // lanes 0..50
    float a0 = 0.f, a1 = 0.f, a2 = 0.f, a3 = 0.f;

    for (int base = begin; base < end; base += 64) {
        int n = end - base; if (n > 64) n = 64;
        unsigned rec = 0u;
        if (lane < n) rec = recs[base + lane];
        int poff = (int)(rec & 0x1FFFFu) * PDE + (int)((rec >> 17) & 7u) * DD;  // elems
        int goff = (int)(rec >> 20) * GDP;                                      // elems

        for (int jj = 0; jj < n; jj += 4) {
            int po[4], go[4];
            #pragma unroll
            for (int u = 0; u < 4; ++u) {
                int j = jj + u; if (j >= n) j = jj;     // clamped dups: L1-hit, unused
                po[u] = __shfl(poff, j);
                go[u] = __shfl(goff, j);
            }
            uint2 pv[4], gv[4];
            #pragma unroll
            for (int u = 0; u < 4; ++u) {
                pv[u] = make_uint2(0u, 0u);
                gv[u] = make_uint2(0u, 0u);
                if (act) {
                    pv[u] = *(const uint2*)&prop[po[u] + d];
                    gv[u] = *(const uint2*)&gat[go[u] + d];
                }
            }
            #pragma unroll
            for (int u = 0; u < 4; ++u) {
                if (jj + u < n || u == 0) {             // n wave-uniform: scalar branch
                    float2 g01 = __half22float2(*(const __half2*)&gv[u].x);
                    float2 g23 = __half22float2(*(const __half2*)&gv[u].y);
                    a0 += __uint_as_float(pv[u].x << 16)         * g01.x;
                    a1 += __uint_as_float(pv[u].x & 0xffff0000u) * g01.y;
                    a2 += __uint_as_float(pv[u].y << 16)         * g23.x;
                    a3 += __uint_as_float(pv[u].y & 0xffff0000u) * g23.y;
                }
            }
        }
    }

    float div = (c == 0 ? 1.0f : (float)c) + 1e-8f;
    float inv = 1.0f / div;
    if (act) {
        float* orow = out + (size_t)wid * DD;
        *(float2*)&orow[d] = make_float2(a0 * inv, a1 * inv);
        if (d + 2 < DD) *(float2*)&orow[d + 2] = make_float2(a2 * inv, a3 * inv);
    }
}

extern "C" void kernel_launch(void* const* d_in, const int* in_sizes, int n_in,
                              void* d_out, int out_size, void* d_ws, size_t ws_size,
                              hipStream_t stream) {
    const float* node_states = (const float*)d_in[0];
    const int*   edges       = (const int*)d_in[1];
    const int*   pos_lists   = (const int*)d_in[2];
    const float* W_transform = (const float*)d_in[3];
    const float* b_transform = (const float*)d_in[4];
    const float* W_pos       = (const float*)d_in[5];
    const float* b_pos       = (const float*)d_in[6];
    float* out = (float*)d_out;

    // workspace layout (16B-aligned blocks)
    char* ws = (char*)d_ws;
    unsigned short* gat = (unsigned short*)ws;  ws += (size_t)NPOS * GDP * 2;  // 208,896 B
    int* count  = (int*)ws;                     ws += (size_t)NN * 4;          // 400,000 B
    int* start  = (int*)ws;                     ws += (size_t)NN * 4;          // 400,000 B
    int* cursor = (int*)ws;                     ws += 16;
    unsigned short* Bt  = (unsigned short*)ws;  ws += (size_t)NP * KP * 2;     // 573,440 B
    unsigned short* Abf = (unsigned short*)ws;  ws += (size_t)NNP * KP * 2;    // 44,843,008 B
    unsigned* recs = (unsigned*)ws;             ws += (size_t)NE * 4;          // 4,800,000 B
    unsigned short* prop = (unsigned short*)ws;                                // 243,200,000 B

    hipMemsetAsync(count, 0, NN * sizeof(int), stream);
    hipMemsetAsync(cursor, 0, sizeof(int), stream);

    // 1. gating | convB | convA | count   (independent; count hidden under convA)
    fused_prep<<<NPOS + NB_CONVB + PREPG * 10, 256, 0, stream>>>(
        W_pos, b_pos, gat, W_transform, Bt, node_states, Abf, edges, count);

    // 2. segment allocation (needs count)
    alloc_kernel<<<(NN + 255) / 256, 256, 0, stream>>>(count, start, cursor);

    // 3. gemm then scatter (concatenated; scatter fills the gemm drain tail)
    fused_main<<<GEMM_WGS + NB_SCAT, 256, 0, stream>>>(
        Abf, Bt, b_transform, prop, edges, pos_lists, start, recs);

    // 4. gather (needs everything)
    gather_kernel<<<(NN + 3) / 4, 256, 0, stream>>>(prop, gat, count, start, recs, out);
}